// Round 3
// baseline (2756.006 us; speedup 1.0000x reference)
//
#include <hip/hip_runtime.h>
#include <math.h>

// G=128, S=32, P=16, D=768, C=256, NH=4, OUT=7; NR = G*P = 2048
#define NG 128
#define NS 32
#define NP 16
#define ND 768
#define NC 256
#define NHD 4
#define NOUT 7
#define NR 2048

typedef unsigned short ushortT;
typedef short bf16x8 __attribute__((ext_vector_type(8)));
typedef float f32x4 __attribute__((ext_vector_type(4)));

__device__ __forceinline__ ushortT f2b(float f) {
    union { float f; unsigned u; } v; v.f = f;
    unsigned r = (v.u + 0x7FFF + ((v.u >> 16) & 1)) >> 16;
    return (ushortT)r;
}
__device__ __forceinline__ float b2f(ushortT u) {
    union { unsigned u; float f; } v; v.u = ((unsigned)u) << 16; return v.f;
}
__device__ __forceinline__ float sigf(float v) { return 1.f / (1.f + expf(-v)); }

#define MFMA16(a, b, c) __builtin_amdgcn_mfma_f32_16x16x32_bf16((a), (b), (c), 0, 0, 0)

// ---------------------------------------------------------------------------
// Generic bf16 MFMA GEMM, 64x64 tile (prep W_ug + step-0 GAT only).
// A [M,K] bf16 row-major; Bt [N,K] bf16; out fp32 and/or bf16.
// ---------------------------------------------------------------------------
__global__ __launch_bounds__(256) void bgemm_kernel(
    const ushortT* __restrict__ A, const ushortT* __restrict__ Bt,
    const float* __restrict__ bias, float* __restrict__ outF,
    ushortT* __restrict__ outH, int N, int K, int act)
{
    __shared__ short As[64 * 40];
    __shared__ short Bs[64 * 40];
    const int tid = threadIdx.x;
    const int lane = tid & 63, wid = tid >> 6;
    const int quad = lane >> 4, l15 = lane & 15;
    const int row0 = blockIdx.y * 64, col0 = blockIdx.x * 64;
    const int mh = (wid & 1) * 32, nh = (wid >> 1) * 32;
    const int sr = tid >> 2, skq = (tid & 3) * 8;
    const ushortT* aptr = A + (size_t)(row0 + sr) * K;
    const ushortT* bptr = Bt + (size_t)(col0 + sr) * K;

    f32x4 acc[2][2];
    for (int i = 0; i < 2; ++i)
        for (int j = 0; j < 2; ++j) acc[i][j] = (f32x4){0.f, 0.f, 0.f, 0.f};

    for (int kk = 0; kk < K; kk += 32) {
        __syncthreads();
        *(uint4*)&As[sr * 40 + skq] = *(const uint4*)(aptr + kk + skq);
        *(uint4*)&Bs[sr * 40 + skq] = *(const uint4*)(bptr + kk + skq);
        __syncthreads();
        bf16x8 af0 = *(const bf16x8*)&As[(mh + l15) * 40 + quad * 8];
        bf16x8 af1 = *(const bf16x8*)&As[(mh + 16 + l15) * 40 + quad * 8];
        bf16x8 bf0 = *(const bf16x8*)&Bs[(nh + l15) * 40 + quad * 8];
        bf16x8 bf1 = *(const bf16x8*)&Bs[(nh + 16 + l15) * 40 + quad * 8];
        acc[0][0] = MFMA16(af0, bf0, acc[0][0]);
        acc[0][1] = MFMA16(af0, bf1, acc[0][1]);
        acc[1][0] = MFMA16(af1, bf0, acc[1][0]);
        acc[1][1] = MFMA16(af1, bf1, acc[1][1]);
    }
#pragma unroll
    for (int mt = 0; mt < 2; ++mt)
#pragma unroll
        for (int nt = 0; nt < 2; ++nt) {
            const int gc = col0 + nh + nt * 16 + l15;
            const float bv = bias ? bias[gc] : 0.f;
#pragma unroll
            for (int r = 0; r < 4; ++r) {
                const int gr = row0 + mh + mt * 16 + quad * 4 + r;
                float v = acc[mt][nt][r] + bv;
                if (act) v = fmaxf(v, 0.f);
                if (outF) outF[(size_t)gr * N + gc] = v;
                if (outH) outH[(size_t)gr * N + gc] = f2b(v);
            }
        }
}

// ---------------------------------------------------------------------------
// Fused GRU step 1: gi = m@Wih^T, gh = h@Whh^T, gate math, h in place.
// grid (256/64, 2048/32) = (4, 64).
// ---------------------------------------------------------------------------
__global__ __launch_bounds__(256) void gru1_mfma_kernel(
    const ushortT* __restrict__ mB, const ushortT* __restrict__ hB,
    const ushortT* __restrict__ WihB, const ushortT* __restrict__ WhhB,
    const float* __restrict__ bih, const float* __restrict__ bhh,
    float* __restrict__ hF, ushortT* __restrict__ hBout)
{
    __shared__ short As[2 * 32 * 264];
    __shared__ short Bs[384 * 40];
    const int tid = threadIdx.x;
    const int lane = tid & 63, wid = tid >> 6;
    const int quad = lane >> 4, l15 = lane & 15;
    const int row0 = blockIdx.y * 32;
    const int n0 = blockIdx.x * 64;
    const int mt = wid & 1, nhh = (wid >> 1) * 32;

    for (int c = tid; c < 2048; c += 256) {
        const int mat = c >> 10, r2 = c & 1023, row = r2 >> 5, kc = (r2 & 31) * 8;
        const ushortT* src = (mat ? hB : mB) + (size_t)(row0 + row) * NC + kc;
        *(uint4*)&As[mat * 8448 + row * 264 + kc] = *(const uint4*)src;
    }
    f32x4 acc[2][3][2];
    for (int w = 0; w < 2; ++w)
        for (int g = 0; g < 3; ++g)
            for (int n = 0; n < 2; ++n) acc[w][g][n] = (f32x4){0.f, 0.f, 0.f, 0.f};

    for (int kk = 0; kk < 256; kk += 32) {
        __syncthreads();
        for (int c = tid; c < 1536; c += 256) {
            const int j = c >> 2, kq = (c & 3) * 8;
            const int w = j / 192, j2 = j - w * 192, gt = j2 >> 6, nloc = j2 & 63;
            const ushortT* src = (w ? WhhB : WihB) +
                (size_t)(gt * 256 + n0 + nloc) * NC + kk + kq;
            *(uint4*)&Bs[j * 40 + kq] = *(const uint4*)src;
        }
        __syncthreads();
        bf16x8 af0 = *(const bf16x8*)&As[(mt * 16 + l15) * 264 + kk + quad * 8];
        bf16x8 af1 = *(const bf16x8*)&As[8448 + (mt * 16 + l15) * 264 + kk + quad * 8];
#pragma unroll
        for (int gt = 0; gt < 3; ++gt)
#pragma unroll
            for (int nt = 0; nt < 2; ++nt) {
                const int jb = gt * 64 + nhh + nt * 16 + l15;
                bf16x8 b0 = *(const bf16x8*)&Bs[jb * 40 + quad * 8];
                bf16x8 b1 = *(const bf16x8*)&Bs[(192 + jb) * 40 + quad * 8];
                acc[0][gt][nt] = MFMA16(af0, b0, acc[0][gt][nt]);
                acc[1][gt][nt] = MFMA16(af1, b1, acc[1][gt][nt]);
            }
    }
#pragma unroll
    for (int nt = 0; nt < 2; ++nt) {
        const int c = n0 + nhh + nt * 16 + l15;
        const float br = bih[c], bz = bih[256 + c], bn = bih[512 + c];
        const float cr = bhh[c], cz = bhh[256 + c], cn = bhh[512 + c];
#pragma unroll
        for (int r = 0; r < 4; ++r) {
            const int grow = row0 + mt * 16 + quad * 4 + r;
            const size_t idx = (size_t)grow * NC + c;
            const float hold = hF[idx];
            const float rg = sigf(acc[0][0][nt][r] + br + acc[1][0][nt][r] + cr);
            const float zg = sigf(acc[0][1][nt][r] + bz + acc[1][1][nt][r] + cz);
            const float ng = tanhf(acc[0][2][nt][r] + bn + rg * (acc[1][2][nt][r] + cn));
            const float hn = (1.f - zg) * ng + zg * hold;
            hF[idx] = hn;
            hBout[idx] = f2b(hn);
        }
    }
}

// ---------------------------------------------------------------------------
// Fused GRU step 2 (zero input): h_nxt bf16 + compact speaker rows h0c.
// ---------------------------------------------------------------------------
__global__ __launch_bounds__(256) void gru2_mfma_kernel(
    const ushortT* __restrict__ hB, const ushortT* __restrict__ WhhB,
    const float* __restrict__ bih, const float* __restrict__ bhh,
    const float* __restrict__ hF, ushortT* __restrict__ hnB,
    ushortT* __restrict__ h0c)
{
    __shared__ short As[32 * 264];
    __shared__ short Bs[192 * 40];
    const int tid = threadIdx.x;
    const int lane = tid & 63, wid = tid >> 6;
    const int quad = lane >> 4, l15 = lane & 15;
    const int row0 = blockIdx.y * 32;
    const int n0 = blockIdx.x * 64;
    const int mt = wid & 1, nhh = (wid >> 1) * 32;

    for (int c = tid; c < 1024; c += 256) {
        const int row = c >> 5, kc = (c & 31) * 8;
        *(uint4*)&As[row * 264 + kc] =
            *(const uint4*)(hB + (size_t)(row0 + row) * NC + kc);
    }
    f32x4 acc[3][2];
    for (int g = 0; g < 3; ++g)
        for (int n = 0; n < 2; ++n) acc[g][n] = (f32x4){0.f, 0.f, 0.f, 0.f};

    for (int kk = 0; kk < 256; kk += 32) {
        __syncthreads();
        for (int c = tid; c < 768; c += 256) {
            const int j = c >> 2, kq = (c & 3) * 8;
            const int gt = j >> 6, nloc = j & 63;
            *(uint4*)&Bs[j * 40 + kq] =
                *(const uint4*)(WhhB + (size_t)(gt * 256 + n0 + nloc) * NC + kk + kq);
        }
        __syncthreads();
        bf16x8 af = *(const bf16x8*)&As[(mt * 16 + l15) * 264 + kk + quad * 8];
#pragma unroll
        for (int gt = 0; gt < 3; ++gt)
#pragma unroll
            for (int nt = 0; nt < 2; ++nt) {
                const int jb = gt * 64 + nhh + nt * 16 + l15;
                bf16x8 b = *(const bf16x8*)&Bs[jb * 40 + quad * 8];
                acc[gt][nt] = MFMA16(af, b, acc[gt][nt]);
            }
    }
#pragma unroll
    for (int nt = 0; nt < 2; ++nt) {
        const int c = n0 + nhh + nt * 16 + l15;
        const float br = bih[c], bz = bih[256 + c], bn = bih[512 + c];
        const float cr = bhh[c], cz = bhh[256 + c], cn = bhh[512 + c];
#pragma unroll
        for (int r = 0; r < 4; ++r) {
            const int grow = row0 + mt * 16 + quad * 4 + r;
            const size_t idx = (size_t)grow * NC + c;
            const float rg = sigf(br + acc[0][nt][r] + cr);
            const float zg = sigf(bz + acc[1][nt][r] + cz);
            const float ng = tanhf(bn + rg * (acc[2][nt][r] + cn));
            const float hv = (1.f - zg) * ng + zg * hF[idx];
            const ushortT hb = f2b(hv);
            hnB[idx] = hb;
            if ((grow & 15) == 0) h0c[(size_t)(grow >> 4) * NC + c] = hb;
        }
    }
}

// ---------------------------------------------------------------------------
// Speaker path: spk = relu(h0c @ Wus + bus) [128x768] (LDS), hs = spk @ gatW
// [128x1024] bf16. grid (1024/128, 128/16) = (8, 8).
// ---------------------------------------------------------------------------
__global__ __launch_bounds__(256) void spkgat_kernel(
    const ushortT* __restrict__ h0c, const ushortT* __restrict__ WusB,
    const float* __restrict__ bus, const ushortT* __restrict__ gatB,
    ushortT* __restrict__ hs)
{
    __shared__ short h0s[16 * 264];
    __shared__ short spks[16 * 776];
    const int tid = threadIdx.x;
    const int lane = tid & 63, wid = tid >> 6;
    const int quad = lane >> 4, l15 = lane & 15;
    const int rows0 = blockIdx.y * 16, cols0 = blockIdx.x * 128;

    for (int c = tid; c < 512; c += 256) {
        const int row = c >> 5, kc = (c & 31) * 8;
        *(uint4*)&h0s[row * 264 + kc] =
            *(const uint4*)(h0c + (size_t)(rows0 + row) * NC + kc);
    }
    __syncthreads();
    f32x4 accA[12];
    for (int t = 0; t < 12; ++t) accA[t] = (f32x4){0.f, 0.f, 0.f, 0.f};
    for (int kk = 0; kk < NC; kk += 32) {
        bf16x8 af = *(const bf16x8*)&h0s[l15 * 264 + kk + quad * 8];
#pragma unroll
        for (int t = 0; t < 12; ++t) {
            const int col = wid * 192 + t * 16 + l15;
            bf16x8 b = *(const bf16x8*)(WusB + (size_t)col * NC + kk + quad * 8);
            accA[t] = MFMA16(af, b, accA[t]);
        }
    }
#pragma unroll
    for (int t = 0; t < 12; ++t) {
        const int col = wid * 192 + t * 16 + l15;
        const float bv = bus[col];
#pragma unroll
        for (int r = 0; r < 4; ++r) {
            float v = accA[t][r] + bv;
            v = fmaxf(v, 0.f);
            spks[(quad * 4 + r) * 776 + col] = f2b(v);
        }
    }
    __syncthreads();
    f32x4 accB[2];
    accB[0] = (f32x4){0.f, 0.f, 0.f, 0.f};
    accB[1] = (f32x4){0.f, 0.f, 0.f, 0.f};
    for (int kk = 0; kk < ND; kk += 32) {
        bf16x8 af = *(const bf16x8*)&spks[l15 * 776 + kk + quad * 8];
#pragma unroll
        for (int t = 0; t < 2; ++t) {
            const int col = cols0 + wid * 32 + t * 16 + l15;
            bf16x8 b = *(const bf16x8*)(gatB + (size_t)col * ND + kk + quad * 8);
            accB[t] = MFMA16(af, b, accB[t]);
        }
    }
#pragma unroll
    for (int t = 0; t < 2; ++t) {
        const int col = cols0 + wid * 32 + t * 16 + l15;
#pragma unroll
        for (int r = 0; r < 4; ++r)
            hs[(size_t)(rows0 + quad * 4 + r) * 1024 + col] = f2b(accB[t][r]);
    }
}

// ---------------------------------------------------------------------------
// Fused GAT GEMM (hn @ W_ug + b_ug, speaker row from hs) + edge softmax +
// head mean + GlobalAttention pool + classifier. One block per graph.
// ---------------------------------------------------------------------------
__global__ __launch_bounds__(256) void gatfin_kernel(
    const ushortT* __restrict__ hnB, const ushortT* __restrict__ hs,
    const ushortT* __restrict__ WugT, const float* __restrict__ bug,
    const float* __restrict__ att_src, const float* __restrict__ att_dst,
    const float* __restrict__ gat_b, const float* __restrict__ attW,
    const float* __restrict__ attb, const float* __restrict__ clsW,
    const float* __restrict__ clsb, ushortT* __restrict__ mB,
    float* __restrict__ outp, int s)
{
    const int g = blockIdx.x, tid = threadIdx.x;
    const int lane = tid & 63, wid = tid >> 6;
    const int quad = lane >> 4, l15 = lane & 15;
    __shared__ short hn_s[16 * 264];
    __shared__ ushortT hb_s[16][1040];
    __shared__ float es_s[16][4], ed_s[16][4];
    __shared__ float m_s[16][260];
    __shared__ float gate_s[16];
    __shared__ float pooled_s[256];

    for (int c = tid; c < 512; c += 256) {
        const int row = c >> 5, kc = (c & 31) * 8;
        *(uint4*)&hn_s[row * 264 + kc] =
            *(const uint4*)(hnB + (size_t)(g * NP + row) * NC + kc);
    }
    __syncthreads();
    f32x4 acc[16];
#pragma unroll
    for (int t = 0; t < 16; ++t) acc[t] = (f32x4){0.f, 0.f, 0.f, 0.f};
    for (int kk = 0; kk < NC; kk += 32) {
        bf16x8 af = *(const bf16x8*)&hn_s[l15 * 264 + kk + quad * 8];
#pragma unroll
        for (int t = 0; t < 16; ++t) {
            const int col = wid * 256 + t * 16 + l15;
            bf16x8 b = *(const bf16x8*)(WugT + (size_t)col * NC + kk + quad * 8);
            acc[t] = MFMA16(af, b, acc[t]);
        }
    }
#pragma unroll
    for (int t = 0; t < 16; ++t) {
        const int col = wid * 256 + t * 16 + l15;
        const float bv = bug[col];
#pragma unroll
        for (int r = 0; r < 4; ++r)
            hb_s[quad * 4 + r][col] = f2b(acc[t][r] + bv);
    }
    __syncthreads();
    for (int c = tid; c < 1024; c += 256) hb_s[0][c] = hs[(size_t)g * 1024 + c];
    __syncthreads();

    for (int pi = 0; pi < 4; ++pi) {
        const int p = wid * 4 + pi;
        float ss[4] = {0.f, 0.f, 0.f, 0.f}, sd[4] = {0.f, 0.f, 0.f, 0.f};
#pragma unroll
        for (int i = 0; i < 16; ++i) {
            const int col = lane + 64 * i;
            const float v = b2f(hb_s[p][col]);
            ss[i >> 2] += v * att_src[col];
            sd[i >> 2] += v * att_dst[col];
        }
        for (int off = 32; off; off >>= 1)
#pragma unroll
            for (int h = 0; h < 4; ++h) {
                ss[h] += __shfl_down(ss[h], off);
                sd[h] += __shfl_down(sd[h], off);
            }
        if (lane == 0)
#pragma unroll
            for (int h = 0; h < 4; ++h) { es_s[p][h] = ss[h]; ed_s[p][h] = sd[h]; }
    }
    __syncthreads();
    {
        const int p = tid >> 4, cb = (tid & 15) * 16;
        float accv[16];
#pragma unroll
        for (int cj = 0; cj < 16; ++cj) accv[cj] = 0.f;
#pragma unroll
        for (int h = 0; h < 4; ++h) {
            float e1 = es_s[0][h] + ed_s[p][h]; e1 = e1 > 0.f ? e1 : 0.2f * e1;
            float e2 = es_s[p][h] + ed_s[p][h]; e2 = e2 > 0.f ? e2 : 0.2f * e2;
            const float mx = fmaxf(e1, e2);
            float w0 = expf(e1 - mx), w1 = expf(e2 - mx);
            const float inv = 1.f / (w0 + w1);
            w0 *= inv; w1 *= inv;
#pragma unroll
            for (int cj = 0; cj < 16; ++cj)
                accv[cj] += w0 * b2f(hb_s[0][h * NC + cb + cj])
                          + w1 * b2f(hb_s[p][h * NC + cb + cj]);
        }
#pragma unroll
        for (int cj = 0; cj < 16; ++cj) {
            const float v = accv[cj] * 0.25f + gat_b[cb + cj];
            m_s[p][cb + cj] = v;
            mB[(size_t)(g * NP + p) * NC + cb + cj] = f2b(v);
        }
    }
    __syncthreads();
    for (int pi = 0; pi < 4; ++pi) {
        const int p = wid * 4 + pi;
        float sg = 0.f;
#pragma unroll
        for (int i = 0; i < 4; ++i) { const int c = lane + 64 * i; sg += m_s[p][c] * attW[c]; }
        for (int off = 32; off; off >>= 1) sg += __shfl_down(sg, off);
        if (lane == 0) gate_s[p] = sg + attb[0];
    }
    __syncthreads();
    float mx = -1e30f;
#pragma unroll
    for (int p = 0; p < 16; ++p) mx = fmaxf(mx, gate_s[p]);
    float ge[16], ssum = 0.f;
#pragma unroll
    for (int p = 0; p < 16; ++p) { ge[p] = expf(gate_s[p] - mx); ssum += ge[p]; }
    const float inv = 1.f / ssum;
    {
        float pc = 0.f;
#pragma unroll
        for (int p = 0; p < 16; ++p) pc += ge[p] * m_s[p][tid];
        pooled_s[tid] = pc * inv;
    }
    __syncthreads();
    const int o = tid >> 5, l32 = tid & 31;
    if (o < NOUT) {
        float a = 0.f;
#pragma unroll
        for (int i = 0; i < 8; ++i) {
            const int c = l32 + 32 * i;
            a += pooled_s[c] * clsW[o * NC + c];
        }
        for (int off = 16; off; off >>= 1) a += __shfl_down(a, off);
        if (l32 == 0) outp[((size_t)g * NS + s) * NOUT + o] = a + clsb[o];
    }
}

// ---------------------------------------------------------------------------
// Standalone fin for step 0 (reads fp32 hbuf from global)
// ---------------------------------------------------------------------------
__global__ __launch_bounds__(256) void fin_kernel(
    const float* __restrict__ hbuf, const float* __restrict__ att_src,
    const float* __restrict__ att_dst, const float* __restrict__ gat_b,
    const float* __restrict__ attW, const float* __restrict__ attb,
    const float* __restrict__ clsW, const float* __restrict__ clsb,
    ushortT* __restrict__ mB, float* __restrict__ outp, int s)
{
    const int g = blockIdx.x, tid = threadIdx.x;
    const int lane = tid & 63, wid = tid >> 6;
    __shared__ float es_s[16][4], ed_s[16][4];
    __shared__ float m_s[16][260];
    __shared__ float gate_s[16];
    __shared__ float pooled_s[256];
    const float* hb = hbuf + (size_t)g * NP * (NHD * NC);

    for (int pi = 0; pi < 4; ++pi) {
        const int p = wid * 4 + pi;
        const float* row = hb + p * (NHD * NC);
        float ss[4] = {0.f, 0.f, 0.f, 0.f}, sd[4] = {0.f, 0.f, 0.f, 0.f};
#pragma unroll
        for (int i = 0; i < 16; ++i) {
            const int col = lane + 64 * i;
            const float v = row[col];
            ss[i >> 2] += v * att_src[col];
            sd[i >> 2] += v * att_dst[col];
        }
        for (int off = 32; off; off >>= 1)
#pragma unroll
            for (int h = 0; h < 4; ++h) {
                ss[h] += __shfl_down(ss[h], off);
                sd[h] += __shfl_down(sd[h], off);
            }
        if (lane == 0)
#pragma unroll
            for (int h = 0; h < 4; ++h) { es_s[p][h] = ss[h]; ed_s[p][h] = sd[h]; }
    }
    __syncthreads();
    {
        const int p = tid >> 4, cb = (tid & 15) * 16;
        float accv[16];
#pragma unroll
        for (int cj = 0; cj < 16; ++cj) accv[cj] = 0.f;
#pragma unroll
        for (int h = 0; h < 4; ++h) {
            float e1 = es_s[0][h] + ed_s[p][h]; e1 = e1 > 0.f ? e1 : 0.2f * e1;
            float e2 = es_s[p][h] + ed_s[p][h]; e2 = e2 > 0.f ? e2 : 0.2f * e2;
            const float mx = fmaxf(e1, e2);
            float w0 = expf(e1 - mx), w1 = expf(e2 - mx);
            const float inv = 1.f / (w0 + w1);
            w0 *= inv; w1 *= inv;
            const float* r0 = hb + h * NC + cb;
            const float* rp = hb + p * (NHD * NC) + h * NC + cb;
#pragma unroll
            for (int cj = 0; cj < 16; ++cj) accv[cj] += w0 * r0[cj] + w1 * rp[cj];
        }
#pragma unroll
        for (int cj = 0; cj < 16; ++cj) {
            const float v = accv[cj] * 0.25f + gat_b[cb + cj];
            m_s[p][cb + cj] = v;
            mB[(size_t)(g * NP + p) * NC + cb + cj] = f2b(v);
        }
    }
    __syncthreads();
    for (int pi = 0; pi < 4; ++pi) {
        const int p = wid * 4 + pi;
        float sg = 0.f;
#pragma unroll
        for (int i = 0; i < 4; ++i) { const int c = lane + 64 * i; sg += m_s[p][c] * attW[c]; }
        for (int off = 32; off; off >>= 1) sg += __shfl_down(sg, off);
        if (lane == 0) gate_s[p] = sg + attb[0];
    }
    __syncthreads();
    float mx = -1e30f;
#pragma unroll
    for (int p = 0; p < 16; ++p) mx = fmaxf(mx, gate_s[p]);
    float ge[16], ssum = 0.f;
#pragma unroll
    for (int p = 0; p < 16; ++p) { ge[p] = expf(gate_s[p] - mx); ssum += ge[p]; }
    const float inv = 1.f / ssum;
    {
        float pc = 0.f;
#pragma unroll
        for (int p = 0; p < 16; ++p) pc += ge[p] * m_s[p][tid];
        pooled_s[tid] = pc * inv;
    }
    __syncthreads();
    const int o = tid >> 5, l32 = tid & 31;
    if (o < NOUT) {
        float a = 0.f;
#pragma unroll
        for (int i = 0; i < 8; ++i) {
            const int c = l32 + 32 * i;
            a += pooled_s[c] * clsW[o * NC + c];
        }
        for (int off = 16; off; off >>= 1) a += __shfl_down(a, off);
        if (l32 == 0) outp[((size_t)g * NS + s) * NOUT + o] = a + clsb[o];
    }
}

// ---------------------------------------------------------------------------
// Prep kernels
// ---------------------------------------------------------------------------
__global__ __launch_bounds__(256) void cast_kernel(const float* __restrict__ a,
                                                   ushortT* __restrict__ b, int n) {
    const int i = blockIdx.x * 256 + threadIdx.x;
    if (i < n) b[i] = f2b(a[i]);
}
__global__ __launch_bounds__(256) void gatT_kernel(const float* __restrict__ gW,
                                                   ushortT* __restrict__ gB) {
    const int idx = blockIdx.x * 256 + threadIdx.x; // < 1024*768
    const int c = idx / ND, d = idx - c * ND;
    gB[idx] = f2b(gW[(size_t)d * (NHD * NC) + c]);
}
__global__ __launch_bounds__(256) void spwc_kernel(const float* __restrict__ spW,
                                                   float* __restrict__ o) {
    const int idx = blockIdx.x * 256 + threadIdx.x; // < 768*768
    const int r = idx / ND, d = idx - r * ND;
    o[idx] = spW[(size_t)r * (2 * ND) + d] + spW[(size_t)r * (2 * ND) + ND + d];
}
// WusB[o][c] = sum_d spWc[o][d] * upW[d][c]
__global__ __launch_bounds__(256) void wus_kernel(const float* __restrict__ spWc,
                                                  const float* __restrict__ upW,
                                                  ushortT* __restrict__ WusB) {
    const int c = threadIdx.x;
    const int o0 = blockIdx.x * 16;
    float acc[16];
#pragma unroll
    for (int i = 0; i < 16; ++i) acc[i] = 0.f;
    for (int d = 0; d < ND; ++d) {
        const float u = upW[(size_t)d * NC + c];
#pragma unroll
        for (int i = 0; i < 16; ++i) acc[i] += spWc[(size_t)(o0 + i) * ND + d] * u;
    }
#pragma unroll
    for (int i = 0; i < 16; ++i) WusB[(size_t)(o0 + i) * NC + c] = f2b(acc[i]);
}
__global__ __launch_bounds__(256) void bus_kernel(const float* __restrict__ spWc,
                                                  const float* __restrict__ up_b,
                                                  const float* __restrict__ sp_b,
                                                  float* __restrict__ bus) {
    const int o = blockIdx.x * 256 + threadIdx.x;
    if (o >= ND) return;
    float a = sp_b[o];
    const float* sr = spWc + (size_t)o * ND;
    for (int d = 0; d < ND; ++d) a += sr[d] * up_b[d];
    bus[o] = a;
}
// upWTc[c][d] = up_W[d][c] as bf16
__global__ __launch_bounds__(256) void upTc_kernel(const float* __restrict__ upW,
                                                   ushortT* __restrict__ o) {
    const int idx = blockIdx.x * 256 + threadIdx.x; // < 256*768
    if (idx >= NC * ND) return;
    const int c = idx / ND, d = idx - c * ND;
    o[idx] = f2b(upW[(size_t)d * NC + c]);
}
// bug[col] = sum_d up_b[d] * gat_W[d][col]
__global__ __launch_bounds__(256) void bug_kernel(const float* __restrict__ gatW,
                                                  const float* __restrict__ up_b,
                                                  float* __restrict__ bug) {
    const int col = blockIdx.x * 256 + threadIdx.x; // < 1024
    float a = 0.f;
    for (int d = 0; d < ND; ++d) a += up_b[d] * gatW[(size_t)d * (NHD * NC) + col];
    bug[col] = a;
}
__global__ __launch_bounds__(256) void x0_kernel(const float* __restrict__ x,
                                                 ushortT* __restrict__ xb) {
    const int idx = blockIdx.x * 256 + threadIdx.x; // < 2048*768
    const int row = idx / ND, d = idx - row * ND;
    const int g = row >> 4, p = row & 15;
    xb[idx] = f2b(x[((size_t)g * (NS * NP) + p) * ND + d]);
}
__global__ __launch_bounds__(256) void zh_kernel(float* hF, ushortT* hB) {
    const int idx = blockIdx.x * 256 + threadIdx.x; // < 2048*256
    hF[idx] = 0.f;
    hB[idx] = 0;
}

// ---------------------------------------------------------------------------
extern "C" void kernel_launch(void* const* d_in, const int* in_sizes, int n_in,
                              void* d_out, int out_size, void* d_ws, size_t ws_size,
                              hipStream_t stream) {
    (void)in_sizes; (void)n_in; (void)out_size; (void)ws_size;
    const float* x       = (const float*)d_in[0];
    const float* gat_W   = (const float*)d_in[1];
    const float* att_src = (const float*)d_in[2];
    const float* att_dst = (const float*)d_in[3];
    const float* gat_b   = (const float*)d_in[4];
    const float* gru_Wih = (const float*)d_in[5];
    const float* gru_Whh = (const float*)d_in[6];
    const float* gru_bih = (const float*)d_in[7];
    const float* gru_bhh = (const float*)d_in[8];
    const float* up_W    = (const float*)d_in[9];
    const float* up_b    = (const float*)d_in[10];
    const float* sp_W    = (const float*)d_in[11];
    const float* sp_b    = (const float*)d_in[12];
    const float* att_W   = (const float*)d_in[13];
    const float* att_b   = (const float*)d_in[14];
    const float* cls_W   = (const float*)d_in[15];
    const float* cls_b   = (const float*)d_in[16];
    float* outp = (float*)d_out;

    char* w = (char*)d_ws;
    ushortT* xb    = (ushortT*)w; w += (size_t)NR * ND * 2;
    ushortT* WihB  = (ushortT*)w; w += (size_t)(3 * NC) * NC * 2;
    ushortT* WhhB  = (ushortT*)w; w += (size_t)(3 * NC) * NC * 2;
    ushortT* gatB  = (ushortT*)w; w += (size_t)(NHD * NC) * ND * 2;
    ushortT* WusB  = (ushortT*)w; w += (size_t)ND * NC * 2;
    ushortT* upWTc = (ushortT*)w; w += (size_t)NC * ND * 2;
    ushortT* WugT  = (ushortT*)w; w += (size_t)(NHD * NC) * NC * 2;
    float*   spWc  = (float*)w;   w += (size_t)ND * ND * 4;
    float*   bus   = (float*)w;   w += (size_t)ND * 4;
    float*   bug   = (float*)w;   w += (size_t)(NHD * NC) * 4;
    float*   hF    = (float*)w;   w += (size_t)NR * NC * 4;
    ushortT* hB    = (ushortT*)w; w += (size_t)NR * NC * 2;
    ushortT* hnB   = (ushortT*)w; w += (size_t)NR * NC * 2;
    ushortT* h0c   = (ushortT*)w; w += (size_t)NG * NC * 2;
    ushortT* hs    = (ushortT*)w; w += (size_t)NG * (NHD * NC) * 2;
    float*   hbuf  = (float*)w;   w += (size_t)NR * (NHD * NC) * 4;
    ushortT* mB    = (ushortT*)w; w += (size_t)NR * NC * 2;

    // ---- prep ----
    cast_kernel<<<768, 256, 0, stream>>>(gru_Wih, WihB, 3 * NC * NC);
    cast_kernel<<<768, 256, 0, stream>>>(gru_Whh, WhhB, 3 * NC * NC);
    gatT_kernel<<<(NHD * NC * ND) / 256, 256, 0, stream>>>(gat_W, gatB);
    spwc_kernel<<<(ND * ND) / 256, 256, 0, stream>>>(sp_W, spWc);
    wus_kernel<<<ND / 16, 256, 0, stream>>>(spWc, up_W, WusB);
    bus_kernel<<<3, 256, 0, stream>>>(spWc, up_b, sp_b, bus);
    upTc_kernel<<<(NC * ND) / 256, 256, 0, stream>>>(up_W, upWTc);
    // W_ug = gatB [1024x768] @ upWTc^T -> WugT [1024][256] bf16
    bgemm_kernel<<<dim3(NC / 64, (NHD * NC) / 64), 256, 0, stream>>>(
        gatB, upWTc, nullptr, nullptr, WugT, NC, ND, 0);
    bug_kernel<<<4, 256, 0, stream>>>(gat_W, up_b, bug);
    x0_kernel<<<(NR * ND) / 256, 256, 0, stream>>>(x, xb);
    zh_kernel<<<(NR * NC) / 256, 256, 0, stream>>>(hF, hB);

    // ---- step 0: m0 = GAT(x0); pool+classify s=0 ----
    bgemm_kernel<<<dim3((NHD * NC) / 64, NR / 64), 256, 0, stream>>>(
        xb, gatB, nullptr, hbuf, nullptr, NHD * NC, ND, 0);
    fin_kernel<<<NG, 256, 0, stream>>>(hbuf, att_src, att_dst, gat_b,
                                       att_W, att_b, cls_W, cls_b, mB, outp, 0);

    // ---- steps 1..31 ----
    for (int j = 1; j < NS; ++j) {
        gru1_mfma_kernel<<<dim3(NC / 64, NR / 32), 256, 0, stream>>>(
            mB, hB, WihB, WhhB, gru_bih, gru_bhh, hF, hB);
        gru2_mfma_kernel<<<dim3(NC / 64, NR / 32), 256, 0, stream>>>(
            hB, WhhB, gru_bih, gru_bhh, hF, hnB, h0c);
        spkgat_kernel<<<dim3(8, 8), 256, 0, stream>>>(h0c, WusB, bus, gatB, hs);
        gatfin_kernel<<<NG, 256, 0, stream>>>(hnB, hs, WugT, bug,
                                              att_src, att_dst, gat_b, att_W,
                                              att_b, cls_W, cls_b, mB, outp, j);
    }
}